// Round 6
// baseline (371.406 us; speedup 1.0000x reference)
//
#include <hip/hip_runtime.h>
#include <hip/hip_bf16.h>
#include <math.h>

typedef __bf16 bf16_t;
typedef bf16_t bf16x2 __attribute__((ext_vector_type(2)));
typedef bf16_t bf16x8 __attribute__((ext_vector_type(8)));
typedef float  f32x4  __attribute__((ext_vector_type(4)));
typedef int    i32x4  __attribute__((ext_vector_type(4)));
typedef unsigned int u32;

#define SEQ 200
#define DD  64

#define MFMA(a, b, c) __builtin_amdgcn_mfma_f32_16x16x32_bf16((a), (b), (c), 0, 0, 0)

// ---------------- prep kernel (1 block): weight transforms ----------------
// Wbc/W1dt rows are PERMUTED so stage-1's packed MFMA output IS stage-2's
// B-fragment: storage row (16j + m) holds global n-column
//   nperm(j,m) = (j&1)*4 + (j>>1)*32 + 8*(m>>2) + (m&3)
__global__ __launch_bounds__(256) void prep_kernel(
    const float* __restrict__ W1, const float* __restrict__ W2,
    bf16_t* __restrict__ Wbc, bf16_t* __restrict__ W1dt,
    bf16_t* __restrict__ W2t, float* __restrict__ W1sT)
{
  const int tid = threadIdx.x;
  for (int i = tid; i < 64 * 64; i += 256) {
    int rp = i >> 6, k = i & 63;
    int j = rp >> 4, mm = rp & 15;
    int n = ((j & 1) << 2) | ((j >> 1) << 5) | ((mm >> 2) << 3) | (mm & 3);
    Wbc[i]  = (bf16_t)(W1[(64 + k) * 64 + n] - W1[(128 + k) * 64 + n]);
    W1dt[i] = (bf16_t)(W1[(192 + k) * 64 + n]);
    // W1sT unpermuted (Q gathered by global n): W1sT[n][d] = W1[d][n]+W1[128+d][n]
    W1sT[i] = W1[k * 64 + rp] + W1[(128 + k) * 64 + rp];
  }
  for (int i = tid; i < 32 * 64; i += 256) {
    int n = i >> 6, k = i & 63;
    W2t[i] = (bf16_t)(W2[k * 32 + n]);
  }
}

__device__ __forceinline__ u32 pk2(float x, float y) {
  bf16x2 t;
  t[0] = (bf16_t)fmaxf(x, 0.f);
  t[1] = (bf16_t)fmaxf(y, 0.f);
  return __builtin_bit_cast(u32, t);
}

#define XR4(v) { v += __shfl_xor(v, 1); v += __shfl_xor(v, 2); \
                 v += __shfl_xor(v, 4); v += __shfl_xor(v, 8); }
#define XM4(v) { v = fmaxf(v, __shfl_xor(v, 1)); v = fmaxf(v, __shfl_xor(v, 2)); \
                 v = fmaxf(v, __shfl_xor(v, 4)); v = fmaxf(v, __shfl_xor(v, 8)); }

// load one 16-row tile of Xu into named float4 regs (row clamped; invalid rows
// are masked via lv=-inf so their values only need to be finite)
#define LOADT(t, Y0, Y1, Y2, Y3) do {                                          \
    int row_ = 16 * (t) + l16;                                                 \
    row_ = row_ < SEQ ? row_ : (SEQ - 1);                                      \
    const float4* p_ = Xr + (row_ * 16 + 2 * g);                               \
    Y0 = p_[0]; Y1 = p_[1]; Y2 = p_[8]; Y3 = p_[9];                            \
  } while (0)

// per-tile pipeline, 2 cross-lane ops in the hot path:
// stage1 (swapped, perm-packed, Q in C-operand) -> stage2 (swapped) ->
// per-lane stage3 + 2-shfl reduce -> deferred-max online softmax + pooling
#define PROC(MASKED, Y0, Y1, Y2, Y3) do {                                      \
    bf16x8 a0_, a1_;                                                           \
    a0_[0]=(bf16_t)Y0.x; a0_[1]=(bf16_t)Y0.y; a0_[2]=(bf16_t)Y0.z; a0_[3]=(bf16_t)Y0.w; \
    a0_[4]=(bf16_t)Y1.x; a0_[5]=(bf16_t)Y1.y; a0_[6]=(bf16_t)Y1.z; a0_[7]=(bf16_t)Y1.w; \
    a1_[0]=(bf16_t)Y2.x; a1_[1]=(bf16_t)Y2.y; a1_[2]=(bf16_t)Y2.z; a1_[3]=(bf16_t)Y2.w; \
    a1_[4]=(bf16_t)Y3.x; a1_[5]=(bf16_t)Y3.y; a1_[6]=(bf16_t)Y3.z; a1_[7]=(bf16_t)Y3.w; \
    f32x4 q0_ = {Q00, Q01, Q02, Q03};                                          \
    f32x4 q1_ = {Q10, Q11, Q12, Q13};                                          \
    f32x4 q2_ = {Q20, Q21, Q22, Q23};                                          \
    f32x4 q3_ = {Q30, Q31, Q32, Q33};                                          \
    f32x4 zz_ = {0.f, 0.f, 0.f, 0.f};                                          \
    f32x4 c0_ = MFMA(bB00, a0_, q0_); c0_ = MFMA(bB01, a1_, c0_);              \
    f32x4 c1_ = MFMA(bB10, a0_, q1_); c1_ = MFMA(bB11, a1_, c1_);              \
    f32x4 c2_ = MFMA(bB20, a0_, q2_); c2_ = MFMA(bB21, a1_, c2_);              \
    f32x4 c3_ = MFMA(bB30, a0_, q3_); c3_ = MFMA(bB31, a1_, c3_);              \
    i32x4 f0_ = { (int)pk2(c0_[0], c0_[1]), (int)pk2(c0_[2], c0_[3]),          \
                  (int)pk2(c1_[0], c1_[1]), (int)pk2(c1_[2], c1_[3]) };        \
    i32x4 f1_ = { (int)pk2(c2_[0], c2_[1]), (int)pk2(c2_[2], c2_[3]),          \
                  (int)pk2(c3_[0], c3_[1]), (int)pk2(c3_[2], c3_[3]) };        \
    bf16x8 hf0_ = __builtin_bit_cast(bf16x8, f0_);                             \
    bf16x8 hf1_ = __builtin_bit_cast(bf16x8, f1_);                             \
    f32x4 d0_ = MFMA(W2fA0, hf0_, zz_); d0_ = MFMA(W2fA1, hf1_, d0_);          \
    f32x4 d1_ = MFMA(W2fB0, hf0_, zz_); d1_ = MFMA(W2fB1, hf1_, d1_);          \
    float pr_ = fmaxf(d0_[0] + b2lo.x, 0.f) * w3lo.x                           \
              + fmaxf(d0_[1] + b2lo.y, 0.f) * w3lo.y                           \
              + fmaxf(d0_[2] + b2lo.z, 0.f) * w3lo.z                           \
              + fmaxf(d0_[3] + b2lo.w, 0.f) * w3lo.w                           \
              + fmaxf(d1_[0] + b2hi.x, 0.f) * w3hi.x                           \
              + fmaxf(d1_[1] + b2hi.y, 0.f) * w3hi.y                           \
              + fmaxf(d1_[2] + b2hi.z, 0.f) * w3hi.z                           \
              + fmaxf(d1_[3] + b2hi.w, 0.f) * w3hi.w;                          \
    pr_ += __shfl_xor(pr_, 16);                                                \
    pr_ += __shfl_xor(pr_, 32);                                                \
    float lv_ = pr_ + b3s;                                                     \
    if (MASKED && l16 >= 8) lv_ = -INFINITY;                                   \
    if (!__all(lv_ <= m + 8.f)) {   /* wave-uniform rare path: max grew */     \
      float tm_ = lv_;                                                         \
      XM4(tm_)                                                                 \
      float mn_ = fmaxf(m, tm_);                                               \
      float al_ = __expf(m - mn_);                                             \
      Zp *= al_;                                                               \
      Pa0 *= al_; Pa1 *= al_; Pa2 *= al_; Pa3 *= al_;                          \
      Pa4 *= al_; Pa5 *= al_; Pa6 *= al_; Pa7 *= al_;                          \
      Pb0 *= al_; Pb1 *= al_; Pb2 *= al_; Pb3 *= al_;                          \
      Pb4 *= al_; Pb5 *= al_; Pb6 *= al_; Pb7 *= al_;                          \
      m = mn_;                                                                 \
    }                                                                          \
    float ee_ = __expf(lv_ - m);                                               \
    Zp += ee_;                                                                 \
    Pa0 += ee_ * (float)a0_[0]; Pa1 += ee_ * (float)a0_[1];                    \
    Pa2 += ee_ * (float)a0_[2]; Pa3 += ee_ * (float)a0_[3];                    \
    Pa4 += ee_ * (float)a0_[4]; Pa5 += ee_ * (float)a0_[5];                    \
    Pa6 += ee_ * (float)a0_[6]; Pa7 += ee_ * (float)a0_[7];                    \
    Pb0 += ee_ * (float)a1_[0]; Pb1 += ee_ * (float)a1_[1];                    \
    Pb2 += ee_ * (float)a1_[2]; Pb3 += ee_ * (float)a1_[3];                    \
    Pb4 += ee_ * (float)a1_[4]; Pb5 += ee_ * (float)a1_[5];                    \
    Pb6 += ee_ * (float)a1_[6]; Pb7 += ee_ * (float)a1_[7];                    \
  } while (0)

// ------- main kernel: one BLOCK per row; 4 waves split the 13 tiles -------
// wave w processes tiles {w, w+4, w+8} (+ tile 12 for w==0); flash-merge at end
__global__ __launch_bounds__(256, 3) void din_kernel(
    const float* __restrict__ em, const float* __restrict__ eu,
    const float* __restrict__ Xu, const float* __restrict__ b1,
    const float* __restrict__ b2, const float* __restrict__ W3,
    const float* __restrict__ b3, const float* __restrict__ gam,
    const float* __restrict__ bet, const float* __restrict__ mmean,
    const float* __restrict__ mvar, const bf16_t* __restrict__ Wbc,
    const bf16_t* __restrict__ W1dt, const bf16_t* __restrict__ W2t,
    const float* __restrict__ W1sT, float* __restrict__ out)
{
  __shared__ float Pl[4][64];     // per-wave unnormalized pooled vectors
  __shared__ float mZs[4][2];     // per-wave (m, Z)

  const int tid  = threadIdx.x;
  const int lane = tid & 63;
  const int wid  = tid >> 6;
  const int g    = lane >> 4;
  const int l16  = lane & 15;
  const int b    = blockIdx.x;

  const float* emr  = em + (size_t)b * DD;
  const float  em_l = emr[lane];
  float4 ef0 = *(const float4*)&emr[8 * g];
  float4 ef1 = *(const float4*)&emr[8 * g + 4];
  float4 ef2 = *(const float4*)&emr[32 + 8 * g];
  float4 ef3 = *(const float4*)&emr[32 + 8 * g + 4];

  // ---- stage-1 folded weight fragments (perm-packed rows) ----
  const bf16x8* Wbc8  = (const bf16x8*)Wbc;
  const bf16x8* W1dt8 = (const bf16x8*)W1dt;
  const bf16x8* W2t8  = (const bf16x8*)W2t;
#define MKBB(NAME, J, C, E0, E1)                                               \
  bf16x8 NAME; {                                                               \
    bf16x8 w_ = Wbc8[(16 * (J) + l16) * 8 + 4 * (C) + g];                      \
    bf16x8 d_ = W1dt8[(16 * (J) + l16) * 8 + 4 * (C) + g];                     \
    NAME[0] = (bf16_t)((float)w_[0] + E0.x * (float)d_[0]);                    \
    NAME[1] = (bf16_t)((float)w_[1] + E0.y * (float)d_[1]);                    \
    NAME[2] = (bf16_t)((float)w_[2] + E0.z * (float)d_[2]);                    \
    NAME[3] = (bf16_t)((float)w_[3] + E0.w * (float)d_[3]);                    \
    NAME[4] = (bf16_t)((float)w_[4] + E1.x * (float)d_[4]);                    \
    NAME[5] = (bf16_t)((float)w_[5] + E1.y * (float)d_[5]);                    \
    NAME[6] = (bf16_t)((float)w_[6] + E1.z * (float)d_[6]);                    \
    NAME[7] = (bf16_t)((float)w_[7] + E1.w * (float)d_[7]);                    \
  }
  MKBB(bB00, 0, 0, ef0, ef1) MKBB(bB01, 0, 1, ef2, ef3)
  MKBB(bB10, 1, 0, ef0, ef1) MKBB(bB11, 1, 1, ef2, ef3)
  MKBB(bB20, 2, 0, ef0, ef1) MKBB(bB21, 2, 1, ef2, ef3)
  MKBB(bB30, 3, 0, ef0, ef1) MKBB(bB31, 3, 1, ef2, ef3)
#undef MKBB

  // stage-2 A-operand (swapped): W2^T fragments. [c-half][n2-tile]
  const bf16x8 W2fA0 = W2t8[l16 * 8 + g];
  const bf16x8 W2fA1 = W2t8[l16 * 8 + 4 + g];
  const bf16x8 W2fB0 = W2t8[(16 + l16) * 8 + g];
  const bf16x8 W2fB1 = W2t8[(16 + l16) * 8 + 4 + g];

  // stage-3 constants indexed by this lane's n2 = 4g+r / 16+4g+r
  const float4 b2lo = *(const float4*)&b2[4 * g];
  const float4 b2hi = *(const float4*)&b2[16 + 4 * g];
  const float4 w3lo = *(const float4*)&W3[4 * g];
  const float4 w3hi = *(const float4*)&W3[16 + 4 * g];
  const float  b3s  = b3[0];

  // ---- Q[n=lane] in exact fp32; em via wave-uniform L1 broadcast loads ----
  float q = b1[lane];
  {
    const float4* wq = (const float4*)(W1sT + lane * 64);
    const float4* eq = (const float4*)emr;
    #pragma unroll
    for (int dd = 0; dd < 16; ++dd) {
      float4 wv = wq[dd];
      float4 ev = eq[dd];   // uniform address: broadcast
      q += ev.x * wv.x + ev.y * wv.y + ev.z * wv.z + ev.w * wv.w;
    }
  }
  // Q gathered with the SAME n-permutation as the weight rows
#define MKQ(NAME, J, R) const float NAME = __shfl(q, (((J)&1)<<2) + (((J)>>1)<<5) + 8*g + (R));
  MKQ(Q00, 0, 0) MKQ(Q01, 0, 1) MKQ(Q02, 0, 2) MKQ(Q03, 0, 3)
  MKQ(Q10, 1, 0) MKQ(Q11, 1, 1) MKQ(Q12, 1, 2) MKQ(Q13, 1, 3)
  MKQ(Q20, 2, 0) MKQ(Q21, 2, 1) MKQ(Q22, 2, 2) MKQ(Q23, 2, 3)
  MKQ(Q30, 3, 0) MKQ(Q31, 3, 1) MKQ(Q32, 3, 2) MKQ(Q33, 3, 3)
#undef MKQ

  // ---- deferred online-softmax + per-lane pooling state ----
  float m = -INFINITY, Zp = 0.f;
  float Pa0 = 0.f, Pa1 = 0.f, Pa2 = 0.f, Pa3 = 0.f;
  float Pa4 = 0.f, Pa5 = 0.f, Pa6 = 0.f, Pa7 = 0.f;
  float Pb0 = 0.f, Pb1 = 0.f, Pb2 = 0.f, Pb3 = 0.f;
  float Pb4 = 0.f, Pb5 = 0.f, Pb6 = 0.f, Pb7 = 0.f;

  const float4* Xr = (const float4*)(Xu + (size_t)b * SEQ * DD);

  // ---- this wave's tiles: wid, wid+4, wid+8 (+12 for wave 0), depth-1 prefetch
  float4 A0, A1, A2, A3, B0, B1, B2, B3;
  LOADT(wid, A0, A1, A2, A3);
  LOADT(wid + 4, B0, B1, B2, B3);
  PROC(0, A0, A1, A2, A3);
  LOADT(wid + 8, A0, A1, A2, A3);
  PROC(0, B0, B1, B2, B3);
  if (wid == 0) {                      // wave-uniform branch
    LOADT(12, B0, B1, B2, B3);
    PROC(0, A0, A1, A2, A3);
    PROC(1, B0, B1, B2, B3);           // tile 12: rows 192..207, mask l16>=8
  } else {
    PROC(0, A0, A1, A2, A3);
  }

  // ---- per-wave finalize: reduce Z and P over the 16 s-classes ----
  float Zw = Zp;
  XR4(Zw)
  XR4(Pa0) XR4(Pa1) XR4(Pa2) XR4(Pa3) XR4(Pa4) XR4(Pa5) XR4(Pa6) XR4(Pa7)
  XR4(Pb0) XR4(Pb1) XR4(Pb2) XR4(Pb3) XR4(Pb4) XR4(Pb5) XR4(Pb6) XR4(Pb7)

  // lane L gathers this wave's unnormalized pooled[d=L] (16 shfl + selects)
  const int  gsrc = (lane >> 3) & 3;
  const int  srcl = 16 * gsrc + l16;
  const int  esel = lane & 7;
  const bool hi   = lane >= 32;
  float pw = 0.f, t_;
  t_ = __shfl(Pa0, srcl); if (!hi && esel == 0) pw = t_;
  t_ = __shfl(Pa1, srcl); if (!hi && esel == 1) pw = t_;
  t_ = __shfl(Pa2, srcl); if (!hi && esel == 2) pw = t_;
  t_ = __shfl(Pa3, srcl); if (!hi && esel == 3) pw = t_;
  t_ = __shfl(Pa4, srcl); if (!hi && esel == 4) pw = t_;
  t_ = __shfl(Pa5, srcl); if (!hi && esel == 5) pw = t_;
  t_ = __shfl(Pa6, srcl); if (!hi && esel == 6) pw = t_;
  t_ = __shfl(Pa7, srcl); if (!hi && esel == 7) pw = t_;
  t_ = __shfl(Pb0, srcl); if (hi && esel == 0) pw = t_;
  t_ = __shfl(Pb1, srcl); if (hi && esel == 1) pw = t_;
  t_ = __shfl(Pb2, srcl); if (hi && esel == 2) pw = t_;
  t_ = __shfl(Pb3, srcl); if (hi && esel == 3) pw = t_;
  t_ = __shfl(Pb4, srcl); if (hi && esel == 4) pw = t_;
  t_ = __shfl(Pb5, srcl); if (hi && esel == 5) pw = t_;
  t_ = __shfl(Pb6, srcl); if (hi && esel == 6) pw = t_;
  t_ = __shfl(Pb7, srcl); if (hi && esel == 7) pw = t_;

  Pl[wid][lane] = pw;
  if (lane == 0) { mZs[wid][0] = m; mZs[wid][1] = Zw; }
  __syncthreads();

  // ---- flash-merge across the 4 waves + BN + concat output (wave 0) ----
  if (wid == 0) {
    float m0 = mZs[0][0], m1 = mZs[1][0], m2 = mZs[2][0], m3 = mZs[3][0];
    float ms = fmaxf(fmaxf(m0, m1), fmaxf(m2, m3));
    float s0 = __expf(m0 - ms), s1 = __expf(m1 - ms);
    float s2 = __expf(m2 - ms), s3 = __expf(m3 - ms);
    float Zt = s0 * mZs[0][1] + s1 * mZs[1][1] + s2 * mZs[2][1] + s3 * mZs[3][1];
    float Pt = s0 * Pl[0][lane] + s1 * Pl[1][lane]
             + s2 * Pl[2][lane] + s3 * Pl[3][lane];
    float pooled = Pt / Zt;

    float o0 = (pooled - mmean[lane]) * rsqrtf(mvar[lane] + 1e-3f) * gam[lane] + bet[lane];
    float o1 = (em_l - mmean[64 + lane]) * rsqrtf(mvar[64 + lane] + 1e-3f) * gam[64 + lane] + bet[64 + lane];
    float o2 = eu[(size_t)b * 64 + lane];
    float* ob = out + (size_t)b * 192;
    ob[lane]       = o0;
    ob[64 + lane]  = o1;
    ob[128 + lane] = o2;
  }
}

extern "C" void kernel_launch(void* const* d_in, const int* in_sizes, int n_in,
                              void* d_out, int out_size, void* d_ws, size_t ws_size,
                              hipStream_t stream) {
  const float* em = (const float*)d_in[0];
  const float* eu = (const float*)d_in[1];
  const float* Xu = (const float*)d_in[2];
  const float* W1 = (const float*)d_in[3];
  const float* b1 = (const float*)d_in[4];
  const float* W2 = (const float*)d_in[5];
  const float* b2 = (const float*)d_in[6];
  const float* W3 = (const float*)d_in[7];
  const float* b3 = (const float*)d_in[8];
  const float* ga = (const float*)d_in[9];
  const float* be = (const float*)d_in[10];
  const float* mm = (const float*)d_in[11];
  const float* mv = (const float*)d_in[12];
  int B = in_sizes[0] / DD;

  float*  W1sT = (float*)d_ws;                          // 16 KB fp32
  bf16_t* Wbc  = (bf16_t*)((char*)d_ws + 64 * 64 * 4);  // 8 KB
  bf16_t* W1dt = Wbc + 64 * 64;                         // 8 KB
  bf16_t* W2t  = W1dt + 64 * 64;                        // 4 KB

  prep_kernel<<<1, 256, 0, stream>>>(W1, W2, Wbc, W1dt, W2t, W1sT);
  din_kernel<<<B, 256, 0, stream>>>(em, eu, Xu, b1, b2, W3, b3, ga, be,
                                    mm, mv, Wbc, W1dt, W2t, W1sT,
                                    (float*)d_out);
}